// Round 7
// baseline (221.334 us; speedup 1.0000x reference)
//
#include <hip/hip_runtime.h>
#include <math.h>

#define NBB 128
#define NAA 5
#define NCC 80
#define NHH 28
#define NWW 28
#define NTT 50
#define CH  85            // 5 + NC
#define HW  784           // NH*NW
#define CELLS 3920        // NA*NH*NW

__constant__ float c_AW[5] = {2.8f, 5.1f, 6.4f, 9.2f, 14.1f};
__constant__ float c_AH[5] = {4.8f, 10.2f, 16.3f, 19.8f, 23.7f};

__device__ __forceinline__ float sigmoidf_(float x) {
    return 1.0f / (1.0f + __expf(-x));
}

__device__ __forceinline__ float smooth_l1(float d) {
    float ad = fabsf(d);
    return (ad < 1.0f) ? 0.5f * d * d : ad - 0.5f;
}

// ---------------------------------------------------------------------------
// Fused kernel v6 = v5 (219.3 us) with LDS-pipe issue cut ~3x:
//  (1) s6 b32 read removed: target area recomputed in-loop as (R-L)*(B-T)
//      (3 VALU on the underutilized VALU pipe vs 5.8cy on the saturated LDS
//      pipe; threshold perturbation ~1e-7 rel, same magnitude as the already-
//      validated division-free reformulation).
//  (2) 2 cells/thread, grid (2,NB) x 1024: one boxS b128 read serves 2 cells.
//      16 waves/CU (4/SIMD) retained -- NOT v3's 8-wave mistake. Stage-1
//      redundancy halves (4x -> 2x). Stage-3: 2 records/wave (64 slots >= 50).
// j-loop LDS: v5 = 32 waves x (b128+b32) -> v6 = 16 waves x b128 per iter.
// ---------------------------------------------------------------------------
__global__ __launch_bounds__(1024) void region_loss_fused(
    const float* __restrict__ out, const float* __restrict__ tgt,
    float* __restrict__ d_out)
{
    __shared__ float  tcA[CELLS];     // scatter grid: tconf of last-winner, else -1
    __shared__ float4 boxS[NTT];      // (L, R, T, B)
    __shared__ int    rCell[NTT];
    __shared__ float  rTx[NTT], rTy[NTT], rTw[NTT], rTh[NTT];
    __shared__ int    rCls[NTT];
    __shared__ unsigned char rActive[NTT];
    __shared__ float  wred[16];

    const int b   = blockIdx.y;
    const int bx  = blockIdx.x;
    const int tid = threadIdx.x;

    // ---- init scatter grid (4 iters/thread at 1024 threads) ----
    for (int i = tid; i < CELLS; i += 1024) tcA[i] = -1.0f;

    // ---- Stage 1: per-target prep (threads 0..49) ----
    float myTc = 0.0f;
    int   myCell = -1;
    if (tid < NTT) {
        const float* tp = tgt + b * NTT * 5 + tid * 5;
        float cls = tp[0];
        float gx = tp[1] * NWW;
        float gy = tp[2] * NHH;
        float gw = tp[3] * NWW;
        float gh = tp[4] * NHH;
        float ga = gw * gh;

        boxS[tid] = make_float4(gx - gw * 0.5f, gx + gw * 0.5f,
                                gy - gh * 0.5f, gy + gh * 0.5f);

        // best anchor: IoU of (0,0,gw,gh) vs (0,0,aw,ah); first max wins
        int best = 0; float bestI = -1.0f;
        #pragma unroll
        for (int a = 0; a < 5; ++a) {
            float inter = fminf(gw, c_AW[a]) * fminf(gh, c_AH[a]);
            float uni   = ga + c_AW[a] * c_AH[a] - inter;
            float iou   = inter / uni;
            if (iou > bestI) { bestI = iou; best = a; }
        }
        int gi = (int)floorf(gx);
        int gj = (int)floorf(gy);
        int cell = (best * NHH + gj) * NWW + gi;

        // assigned predicted box (4 gathered loads)
        const float* op = out + ((size_t)(b * NAA + best) * CH) * HW + gj * NWW + gi;
        float px = sigmoidf_(op[0])      + (float)gi;
        float py = sigmoidf_(op[HW])     + (float)gj;
        float pw = __expf(op[2 * HW]) * c_AW[best];
        float ph = __expf(op[3 * HW]) * c_AH[best];

        float mx = fminf(px - pw * 0.5f, gx - gw * 0.5f);
        float Mx = fmaxf(px + pw * 0.5f, gx + gw * 0.5f);
        float my = fminf(py - ph * 0.5f, gy - gh * 0.5f);
        float My = fmaxf(py + ph * 0.5f, gy + gh * 0.5f);
        float cw  = pw + gw - (Mx - mx);
        float chh = ph + gh - (My - my);
        float inter = (cw > 0.f && chh > 0.f) ? cw * chh : 0.f;
        float uni   = pw * ph + ga - inter;

        myCell = cell;
        myTc   = inter / uni;
        rCell[tid] = cell;
        rTx[tid]   = gx - (float)gi;
        rTy[tid]   = gy - (float)gj;
        rTw[tid]   = __logf(gw / c_AW[best]);
        rTh[tid]   = __logf(gh / c_AH[best]);
        rCls[tid]  = (int)cls;
    }
    __syncthreads();

    // ---- dedup (last-write-wins) + scatter tconf into grid ----
    if (tid < NTT) {
        unsigned char active = 1;
        for (int t2 = tid + 1; t2 < NTT; ++t2)
            if (rCell[t2] == myCell) active = 0;   // later record wins
        rActive[tid] = active;
        if (active) tcA[myCell] = myTc;            // unique per cell: race-free
    }
    __syncthreads();

    // ---- Stage 2: conf loss, TWO cells per thread ----
    float L_[2], R_[2], T_[2], B_[2], C_[2], CF_[2];
    bool  fl_[2];

    #pragma unroll
    for (int k = 0; k < 2; ++k) {
        const int cell = bx * 2048 + (k << 10) + tid;
        fl_[k] = false;
        if (cell < CELLS) {
            int a  = cell / HW;
            int hw = cell - a * HW;
            int wi = hw % NWW;
            int hj = hw / NWW;
            const float* op = out + ((size_t)(b * NAA + a) * CH) * HW + hw;

            float px = sigmoidf_(op[0])  + (float)wi;
            float py = sigmoidf_(op[HW]) + (float)hj;
            float pw = __expf(op[2 * HW]) * c_AW[a];
            float ph = __expf(op[3 * HW]) * c_AH[a];
            CF_[k]   = sigmoidf_(op[4 * HW]);

            L_[k] = px - pw * 0.5f;  R_[k] = px + pw * 0.5f;
            T_[k] = py - ph * 0.5f;  B_[k] = py + ph * 0.5f;
            C_[k] = 0.375f * (pw * ph);
        } else {
            // inert: intersection always 0, threshold unreachable
            L_[k] = 1e30f;  R_[k] = -1e30f;
            T_[k] = 1e30f;  B_[k] = -1e30f;
            C_[k] = 1e30f;  CF_[k] = 0.0f;
        }
    }

    #pragma unroll 5
    for (int j = 0; j < NTT; ++j) {
        float4 bxj = boxS[j];                      // ONE ds_read_b128 / 2 cells
        float sj = 0.375f * ((bxj.y - bxj.x) * (bxj.w - bxj.z));
        #pragma unroll
        for (int k = 0; k < 2; ++k) {
            float cw  = fminf(R_[k], bxj.y) - fmaxf(L_[k], bxj.x);
            float ch2 = fminf(B_[k], bxj.w) - fmaxf(T_[k], bxj.z);
            float inter = fmaxf(cw, 0.f) * fmaxf(ch2, 0.f);
            fl_[k] = fl_[k] || (inter > C_[k] + sj);     // iou > 0.6
        }
    }

    float term = 0.0f;
    #pragma unroll
    for (int k = 0; k < 2; ++k) {
        const int cell = bx * 2048 + (k << 10) + tid;
        if (cell < CELLS) {
            float tc = tcA[cell];                  // one b32 gather per cell
            if (tc > -0.5f) {
                float d = CF_[k] - tc; term += 2.5f * d * d;
            } else if (!fl_[k]) {
                term += 0.5f * CF_[k] * CF_[k];
            }
        }
    }

    // ---- Stage 3: assigned-cell loss, 2 records per wave ----
    const int wave = tid >> 6;
    const int lane = tid & 63;
    float contrib = 0.0f;

    #pragma unroll
    for (int k = 0; k < 2; ++k) {
        const int j3 = bx * 32 + (wave << 1) + k;  // 2*32 = 64 slots >= NTT
        if (j3 < NTT && rActive[j3]) {
            int rc = rCell[j3];
            int a  = rc / HW;
            int hw = rc - a * HW;
            const float* op = out + ((size_t)(b * NAA + a) * CH) * HW + hw;

            // class logits: lane -> c=lane, plus c=64+lane for lane<16
            float l0  = op[(5 + lane) * HW];
            float l1c = (lane < 16) ? op[(5 + 64 + lane) * HW] : -INFINITY;

            float m = fmaxf(l0, l1c);
            for (int o = 32; o >= 1; o >>= 1) m = fmaxf(m, __shfl_xor(m, o));
            float s = __expf(l0 - m) + ((lane < 16) ? __expf(l1c - m) : 0.0f);
            for (int o = 32; o >= 1; o >>= 1) s += __shfl_xor(s, o);

            int t = rCls[j3];                      // wave-uniform
            float lt = (t < 64) ? __shfl(l0, t) : __shfl(l1c, t - 64);
            float logpt = lt - m - __logf(s);
            float pt = __expf(logpt);
            float focal = -(1.0f - pt) * (1.0f - pt) * logpt;

            if (lane == 0) {
                float x = sigmoidf_(op[0]);
                float y = sigmoidf_(op[HW]);
                float w = op[2 * HW];
                float h = op[3 * HW];
                contrib += focal +
                           0.5f * (smooth_l1(x - rTx[j3]) + smooth_l1(y - rTy[j3]) +
                                   smooth_l1(w - rTw[j3]) + smooth_l1(h - rTh[j3]));
            }
        }
    }

    // ---- reduction: wave shuffle + 16-slot LDS + single atomic ----
    float v = term + contrib;                      // contrib nonzero only on lane 0
    #pragma unroll
    for (int o = 32; o >= 1; o >>= 1) v += __shfl_xor(v, o);
    if (lane == 0) wred[wave] = v;
    __syncthreads();
    if (tid == 0) {
        float s = 0.0f;
        #pragma unroll
        for (int w2 = 0; w2 < 16; ++w2) s += wred[w2];
        atomicAdd(d_out, s);
    }
}

extern "C" void kernel_launch(void* const* d_in, const int* in_sizes, int n_in,
                              void* d_out, int out_size, void* d_ws, size_t ws_size,
                              hipStream_t stream) {
    const float* out_p = (const float*)d_in[0];   // (128, 425, 28, 28)
    const float* tgt_p = (const float*)d_in[1];   // (128, 250)
    float* loss = (float*)d_out;

    hipMemsetAsync(loss, 0, (size_t)out_size * sizeof(float), stream);

    region_loss_fused<<<dim3(2, NBB), dim3(1024), 0, stream>>>(
        out_p, tgt_p, loss);
}

// Round 8
// 217.919 us; speedup vs baseline: 1.0157x; 1.0157x over previous
//
#include <hip/hip_runtime.h>
#include <math.h>

#define NBB 128
#define NAA 5
#define NCC 80
#define NHH 28
#define NWW 28
#define NTT 50
#define CH  85            // 5 + NC
#define HW  784           // NH*NW
#define CELLS 3920        // NA*NH*NW

__constant__ float c_AW[5] = {2.8f, 5.1f, 6.4f, 9.2f, 14.1f};
__constant__ float c_AH[5] = {4.8f, 10.2f, 16.3f, 19.8f, 23.7f};

__device__ __forceinline__ float sigmoidf_(float x) {
    return 1.0f / (1.0f + __expf(-x));
}

__device__ __forceinline__ float smooth_l1(float d) {
    float ad = fabsf(d);
    return (ad < 1.0f) ? 0.5f * d * d : ad - 0.5f;
}

// ---------------------------------------------------------------------------
// FINAL kernel = v5 (best measured: 219.3 us).
// Session evidence: timed region = 2 harness-owned 666,400 KB fills at
// 6.5-6.7 TB/s (82-84% of HBM spec = at the ~6.3 TB/s achievable ceiling)
// ~= 206-210 us, + this kernel ~= 9-10 us.
// Structure: grid (4,NB), block 1024 (16 waves; 2 blocks/CU -> 32 waves/CU).
//  Stage 1: threads 0..49 build per-target records in LDS; dedup last-winner;
//           scatter tconf into tcA[3920] grid (init -1).
//  Stage 2: per cell, 50-iter sigil loop (b128 box read/iter; division-free
//           IoU>0.6 test: inter > 0.375*(a1+a2)); assigned-cell lookup is a
//           single b32 gather from tcA (replaced the 50-iter b64 scan; -2.8us).
//  Stage 3: one record per wave: 80-class focal via 64-lane shuffle softmax
//           + smooth-L1 coord loss on lane 0.
//  Reduction: wave shuffle + 16-slot LDS + one atomicAdd per block.
// Variants that regressed (do not retry): 4-cell/256-thr (8 waves/CU, 228.8),
// v_readlane broadcast (SGPR hazard chains, 227.2), 2-cell/half-grid
// (16 waves/CU, 221.3). Occupancy at 32 waves/CU is the binding resource.
// ---------------------------------------------------------------------------
__global__ __launch_bounds__(1024) void region_loss_fused(
    const float* __restrict__ out, const float* __restrict__ tgt,
    float* __restrict__ d_out)
{
    __shared__ float  tcA[CELLS];     // scatter grid: tconf of last-winner, else -1
    __shared__ float4 boxS[NTT];      // (L, R, T, B)
    __shared__ float  s6[NTT];        // 0.375 * gt area
    __shared__ int    rCell[NTT];
    __shared__ float  rTx[NTT], rTy[NTT], rTw[NTT], rTh[NTT];
    __shared__ int    rCls[NTT];
    __shared__ unsigned char rActive[NTT];
    __shared__ float  wred[16];

    const int b   = blockIdx.y;
    const int bx  = blockIdx.x;
    const int tid = threadIdx.x;

    // ---- init scatter grid (4 iters/thread at 1024 threads) ----
    for (int i = tid; i < CELLS; i += 1024) tcA[i] = -1.0f;

    // ---- Stage 1: per-target prep (threads 0..49) ----
    float myTc = 0.0f;
    int   myCell = -1;
    if (tid < NTT) {
        const float* tp = tgt + b * NTT * 5 + tid * 5;
        float cls = tp[0];
        float gx = tp[1] * NWW;
        float gy = tp[2] * NHH;
        float gw = tp[3] * NWW;
        float gh = tp[4] * NHH;
        float ga = gw * gh;

        boxS[tid] = make_float4(gx - gw * 0.5f, gx + gw * 0.5f,
                                gy - gh * 0.5f, gy + gh * 0.5f);
        s6[tid] = 0.375f * ga;        // 0.6/1.6 = 0.375 exactly

        // best anchor: IoU of (0,0,gw,gh) vs (0,0,aw,ah); first max wins
        int best = 0; float bestI = -1.0f;
        #pragma unroll
        for (int a = 0; a < 5; ++a) {
            float inter = fminf(gw, c_AW[a]) * fminf(gh, c_AH[a]);
            float uni   = ga + c_AW[a] * c_AH[a] - inter;
            float iou   = inter / uni;
            if (iou > bestI) { bestI = iou; best = a; }
        }
        int gi = (int)floorf(gx);
        int gj = (int)floorf(gy);
        int cell = (best * NHH + gj) * NWW + gi;

        // assigned predicted box (4 gathered loads)
        const float* op = out + ((size_t)(b * NAA + best) * CH) * HW + gj * NWW + gi;
        float px = sigmoidf_(op[0])      + (float)gi;
        float py = sigmoidf_(op[HW])     + (float)gj;
        float pw = __expf(op[2 * HW]) * c_AW[best];
        float ph = __expf(op[3 * HW]) * c_AH[best];

        float mx = fminf(px - pw * 0.5f, gx - gw * 0.5f);
        float Mx = fmaxf(px + pw * 0.5f, gx + gw * 0.5f);
        float my = fminf(py - ph * 0.5f, gy - gh * 0.5f);
        float My = fmaxf(py + ph * 0.5f, gy + gh * 0.5f);
        float cw  = pw + gw - (Mx - mx);
        float chh = ph + gh - (My - my);
        float inter = (cw > 0.f && chh > 0.f) ? cw * chh : 0.f;
        float uni   = pw * ph + ga - inter;

        myCell = cell;
        myTc   = inter / uni;
        rCell[tid] = cell;
        rTx[tid]   = gx - (float)gi;
        rTy[tid]   = gy - (float)gj;
        rTw[tid]   = __logf(gw / c_AW[best]);
        rTh[tid]   = __logf(gh / c_AH[best]);
        rCls[tid]  = (int)cls;
    }
    __syncthreads();

    // ---- dedup (last-write-wins) + scatter tconf into grid ----
    if (tid < NTT) {
        unsigned char active = 1;
        for (int t2 = tid + 1; t2 < NTT; ++t2)
            if (rCell[t2] == myCell) active = 0;   // later record wins
        rActive[tid] = active;
        if (active) tcA[myCell] = myTc;            // unique per cell: race-free
    }
    __syncthreads();

    // ---- Stage 2: conf loss over cells (sigil loop, LDS b128+b32/iter) ----
    const int cell = bx * 1024 + tid;
    float term = 0.0f;

    if (cell < CELLS) {
        int a  = cell / HW;
        int hw = cell - a * HW;
        int wi = hw % NWW;
        int hj = hw / NWW;
        const float* op = out + ((size_t)(b * NAA + a) * CH) * HW + hw;

        float px   = sigmoidf_(op[0])  + (float)wi;
        float py   = sigmoidf_(op[HW]) + (float)hj;
        float pw   = __expf(op[2 * HW]) * c_AW[a];
        float ph   = __expf(op[3 * HW]) * c_AH[a];
        float conf = sigmoidf_(op[4 * HW]);

        float l1 = px - pw * 0.5f, r1 = px + pw * 0.5f;
        float t1 = py - ph * 0.5f, b1 = py + ph * 0.5f;
        float c1 = 0.375f * (pw * ph);

        bool flag = false;
        #pragma unroll 5
        for (int j = 0; j < NTT; ++j) {
            float4 bxj = boxS[j];                             // ds_read_b128
            float cw  = fminf(r1, bxj.y) - fmaxf(l1, bxj.x);
            float ch2 = fminf(b1, bxj.w) - fmaxf(t1, bxj.z);
            float inter = fmaxf(cw, 0.f) * fmaxf(ch2, 0.f);
            flag = flag || (inter > c1 + s6[j]);              // iou > 0.6
        }

        float tc = tcA[cell];                                 // one b32 gather
        if (tc > -0.5f) {
            float d = conf - tc; term = 2.5f * d * d;
        } else if (!flag) {
            term = 0.5f * conf * conf;
        }
    }

    // ---- Stage 3: assigned-cell loss, one record per wave ----
    const int wave = tid >> 6;
    const int lane = tid & 63;
    const int j3   = bx * 16 + wave;   // 4*16 = 64 slots >= NTT

    float contrib = 0.0f;

    if (j3 < NTT && rActive[j3]) {
        int rc = rCell[j3];
        int a  = rc / HW;
        int hw = rc - a * HW;
        const float* op = out + ((size_t)(b * NAA + a) * CH) * HW + hw;

        // class logits: lane -> c=lane, plus c=64+lane for lane<16
        float l0  = op[(5 + lane) * HW];
        float l1c = (lane < 16) ? op[(5 + 64 + lane) * HW] : -INFINITY;

        float m = fmaxf(l0, l1c);
        for (int o = 32; o >= 1; o >>= 1) m = fmaxf(m, __shfl_xor(m, o));
        float s = __expf(l0 - m) + ((lane < 16) ? __expf(l1c - m) : 0.0f);
        for (int o = 32; o >= 1; o >>= 1) s += __shfl_xor(s, o);

        int t = rCls[j3];                             // wave-uniform
        float lt = (t < 64) ? __shfl(l0, t) : __shfl(l1c, t - 64);
        float logpt = lt - m - __logf(s);
        float pt = __expf(logpt);
        float focal = -(1.0f - pt) * (1.0f - pt) * logpt;

        if (lane == 0) {
            float x = sigmoidf_(op[0]);
            float y = sigmoidf_(op[HW]);
            float w = op[2 * HW];
            float h = op[3 * HW];
            contrib = focal +
                      0.5f * (smooth_l1(x - rTx[j3]) + smooth_l1(y - rTy[j3]) +
                              smooth_l1(w - rTw[j3]) + smooth_l1(h - rTh[j3]));
        }
    }

    // ---- reduction: wave shuffle + 16-slot LDS + single atomic ----
    float v = term + contrib;                      // contrib nonzero only on lane 0
    #pragma unroll
    for (int o = 32; o >= 1; o >>= 1) v += __shfl_xor(v, o);
    if (lane == 0) wred[wave] = v;
    __syncthreads();
    if (tid == 0) {
        float s = 0.0f;
        #pragma unroll
        for (int w2 = 0; w2 < 16; ++w2) s += wred[w2];
        atomicAdd(d_out, s);
    }
}

extern "C" void kernel_launch(void* const* d_in, const int* in_sizes, int n_in,
                              void* d_out, int out_size, void* d_ws, size_t ws_size,
                              hipStream_t stream) {
    const float* out_p = (const float*)d_in[0];   // (128, 425, 28, 28)
    const float* tgt_p = (const float*)d_in[1];   // (128, 250)
    float* loss = (float*)d_out;

    hipMemsetAsync(loss, 0, (size_t)out_size * sizeof(float), stream);

    region_loss_fused<<<dim3(4, NBB), dim3(1024), 0, stream>>>(
        out_p, tgt_p, loss);
}